// Round 7
// baseline (227.534 us; speedup 1.0000x reference)
//
#include <hip/hip_runtime.h>
#include <hip/hip_bf16.h>
#include <math.h>
#include <type_traits>

#define K_DIM 256
using bf16 = __hip_bfloat16;

typedef __attribute__((ext_vector_type(8))) short s8v;   // 8 bf16 (4 VGPRs)
typedef __attribute__((ext_vector_type(4))) float f4v;   // 4 f32 acc

// ---- dtype helpers ------------------------------------------------------
__device__ __forceinline__ float b2f(unsigned short u) {
    return __uint_as_float(((unsigned)u) << 16);
}
__device__ __forceinline__ unsigned short f2b(float f) {   // RNE f32->bf16
    unsigned u = __float_as_uint(f);
    unsigned r = 0x7FFFu + ((u >> 16) & 1u);
    return (unsigned short)((u + r) >> 16);
}
__device__ __forceinline__ float  ld1(const float* p) { return *p; }
__device__ __forceinline__ float  ld1(const bf16*  p) { return b2f(*(const unsigned short*)p); }
__device__ __forceinline__ float4 ld4(const float* p) { return *(const float4*)p; }
__device__ __forceinline__ float4 ld4(const bf16*  p) {
    ushort4 u = *(const ushort4*)p;
    return make_float4(b2f(u.x), b2f(u.y), b2f(u.z), b2f(u.w));
}
__device__ __forceinline__ s8v ldw8(const bf16* p) { return *(const s8v*)p; }

// ---- runtime dtype detection (insurance; evidence says f32) -------------
__device__ __forceinline__ bool detect_bf16(const unsigned* __restrict__ qw) {
    unsigned w = qw[threadIdx.x & 63];
    unsigned t = (w >> 8) & 0x7F;
    bool hit = (t >= 0x3Bu) && (t <= 0x42u);
    unsigned long long m = __ballot(hit);
    return __popcll(m) >= 32;
}

// ---- weight pre-conversion (single merged kernel) ------------------------
// dst1 (wc1): [0,65536) W_value | [65536,131072) W_off | [131072,163840) W_attn
//   | [163840,164096) b_value | [164096,164352) b_off | [164352,164480) b_attn
// dst2 (wc2): [0,65536) W_out | [65536,65792) b_out
#define P1_TOTAL 164480
#define P_TOTAL  230272
__global__ __launch_bounds__(256) void k_prep(
    const unsigned* __restrict__ qd,
    const void* wv, const void* wo, const void* wa,
    const void* bv, const void* bo, const void* ba,
    const void* wout, const void* bout,
    bf16* __restrict__ dst1, bf16* __restrict__ dst2)
{
    const bool isb = detect_bf16(qd);
    const int i4 = (blockIdx.x * 256 + threadIdx.x) * 4;
    if (i4 >= P_TOTAL) return;
    const void* src; int off; bf16* dst;
    if (i4 < P1_TOTAL) {
        dst = dst1 + i4;
        if      (i4 < 65536)  { src = wv; off = i4; }
        else if (i4 < 131072) { src = wo; off = i4 - 65536; }
        else if (i4 < 163840) { src = wa; off = i4 - 131072; }
        else if (i4 < 164096) { src = bv; off = i4 - 163840; }
        else if (i4 < 164352) { src = bo; off = i4 - 164096; }
        else                  { src = ba; off = i4 - 164352; }
    } else {
        const int j = i4 - P1_TOTAL;
        dst = dst2 + j;
        if (j < 65536) { src = wout; off = j; }
        else           { src = bout; off = j - 65536; }
    }
    if (isb) {
        *(ushort4*)dst = *(const ushort4*)((const unsigned short*)src + off);
    } else {
        float4 v = *(const float4*)((const float*)src + off);
        *(ushort4*)dst = make_ushort4(f2b(v.x), f2b(v.y), f2b(v.z), f2b(v.w));
    }
}

// ---- MFMA GEMM ----------------------------------------------------------
// R7: 16-ROW TILES. R4-R6 PMC: gemm12 pinned ~49us with MfmaUtil 5%,
// VALU 7.5%, Occ 22%, HBM 1.3 TB/s -> structural concurrency starvation
// (single round of 1360 blocks, lockstep phases). M=16 doubles blocks and
// waves (2720 blocks, ~1.8 rounds/CU) so staging/compute/epilogue of
// different block-rounds overlap. A-traffic unchanged (M-split only
// duplicates L2-resident weight reads). acc halves -> lower VGPR.
// HMAJOR: C1 written head-major [h=c>>5][Mtot][32ch].
// HM2:    C2 written head-major [h=cc>>4][Mtot][16].
// A1HM:   A1 is read head-major [h][Mtot][32] (bf16 fast path only).
template<typename AT, typename RT, typename CT, int NFRAG, bool ADD_A2, bool SPLIT,
         bool ADD_RES, bool HMAJOR, bool HM2, bool A1HM>
__device__ __forceinline__ void mfma_gemm_body(
    unsigned short* __restrict__ As, int bm,
    const AT* __restrict__ A1, const AT* __restrict__ A2,
    const bf16* __restrict__ W1, const bf16* __restrict__ bias1, CT* __restrict__ C1, int N1,
    const bf16* __restrict__ W2, const bf16* __restrict__ bias2, bf16* __restrict__ C2, int N2,
    const RT* __restrict__ Res, int Mtot)
{
    const int tid = threadIdx.x;

    {   // stage A(+A2) -> bf16 LDS; 16 rows x 256 cols
        const AT* t1 = A1 + (size_t)bm * K_DIM;
        if constexpr (!ADD_A2 && std::is_same<AT, bf16>::value) {
            s8v r[2];
            #pragma unroll
            for (int j = 0; j < 2; ++j) {
                const int e = j * 2048 + tid * 8;
                const int row = e >> 8, col = e & 255;
                const bf16* src;
                if constexpr (A1HM)
                    src = (const bf16*)A1 +
                          ((size_t)(col >> 5) * (size_t)Mtot + (size_t)(bm + row)) * 32 + (col & 31);
                else
                    src = t1 + e;
                r[j] = *(const s8v*)src;
            }
            #pragma unroll
            for (int j = 0; j < 2; ++j) {
                const int e = j * 2048 + tid * 8;
                *(s8v*)&As[(e >> 8) * 264 + (e & 255)] = r[j];
            }
        } else {
            float4 ra[4], rb[4];
            #pragma unroll
            for (int j = 0; j < 4; ++j)
                ra[j] = ld4(t1 + j * 1024 + tid * 4);
            if (ADD_A2) {
                const AT* t2 = A2 + (size_t)bm * K_DIM;
                #pragma unroll
                for (int j = 0; j < 4; ++j)
                    rb[j] = ld4(t2 + j * 1024 + tid * 4);
            }
            #pragma unroll
            for (int j = 0; j < 4; ++j) {
                const int e = j * 1024 + tid * 4;
                float4 v = ra[j];
                if (ADD_A2) { v.x += rb[j].x; v.y += rb[j].y; v.z += rb[j].z; v.w += rb[j].w; }
                *(ushort4*)&As[(e >> 8) * 264 + (e & 255)] =
                    make_ushort4(f2b(v.x), f2b(v.y), f2b(v.z), f2b(v.w));
            }
        }
    }

    const int wv = tid >> 6;
    const int lane = tid & 63;
    const int n15 = lane & 15;
    const int quad = lane >> 4;

    const bf16* Wr[NFRAG];
    int col[NFRAG];
    #pragma unroll
    for (int f = 0; f < NFRAG; ++f) {
        const int c = (wv * NFRAG + f) * 16 + n15;
        col[f] = c;
        if (SPLIT && c >= N1) Wr[f] = W2 + (size_t)(c - N1) * K_DIM;
        else                  Wr[f] = W1 + (size_t)c * K_DIM;
    }

    // prefetch: first weight fragments + bias + Res (latency overlaps the
    // barrier drain below)
    s8v bcur[NFRAG], bnxt[NFRAG];
    #pragma unroll
    for (int f = 0; f < NFRAG; ++f) bcur[f] = ldw8(Wr[f] + quad * 8);

    float bv[NFRAG];
    #pragma unroll
    for (int f = 0; f < NFRAG; ++f) {
        const int c = col[f];
        const bool hi = SPLIT && (c >= N1);
        bv[f] = hi ? ld1(bias2 + (c - N1)) : ld1(bias1 + c);
    }

    float rres[NFRAG][4];
    if constexpr (ADD_RES) {
        #pragma unroll
        for (int f = 0; f < NFRAG; ++f)
            #pragma unroll
            for (int r = 0; r < 4; ++r) {
                const int m = bm + quad * 4 + r;
                rres[f][r] = ld1(Res + (size_t)m * N1 + col[f]);
            }
    }

    __syncthreads();

    const f4v zz = {0.f, 0.f, 0.f, 0.f};
    f4v acc[NFRAG];
    #pragma unroll
    for (int f = 0; f < NFRAG; ++f) acc[f] = zz;

    #pragma unroll
    for (int kk = 0; kk < 8; ++kk) {
        const int k0 = kk * 32 + quad * 8;
        if (kk < 7) {
            #pragma unroll
            for (int f = 0; f < NFRAG; ++f) bnxt[f] = ldw8(Wr[f] + k0 + 32);
        }
        const s8v a = *(const s8v*)&As[n15 * 264 + k0];
        #pragma unroll
        for (int f = 0; f < NFRAG; ++f)
            acc[f] = __builtin_amdgcn_mfma_f32_16x16x32_bf16(a, bcur[f], acc[f], 0, 0, 0);
        if (kk < 7) {
            #pragma unroll
            for (int f = 0; f < NFRAG; ++f) bcur[f] = bnxt[f];
        }
    }

    // ---- coalesced epilogue via LDS C-staging (As is dead) ----
    __syncthreads();   // all waves done reading As

    if constexpr (std::is_same<CT, float>::value) {
        // final GEMM f32 out: 16 rows x 256 f32 staged (16,896 B buffer)
        float* Asf = (float*)As;
        #pragma unroll
        for (int f = 0; f < NFRAG; ++f)
            #pragma unroll
            for (int r = 0; r < 4; ++r) {
                float v = acc[f][r] + bv[f];
                if (ADD_RES) v += rres[f][r];
                Asf[(quad * 4 + r) * 264 + col[f]] = v;
            }
        __syncthreads();
        {
            const int row = tid >> 4;          // 0..15
            const int c16 = tid & 15;
            float* dst = (float*)C1 + (size_t)(bm + row) * 256;
            #pragma unroll
            for (int s = 0; s < 4; ++s) {
                const int eo = (c16 + s * 16) * 4;
                *(float4*)(dst + eo) = *(const float4*)(Asf + row * 264 + eo);
            }
        }
    } else {
        unsigned short* Asu = As;
        // stage C1 cols (c < N1): 16 rows
        #pragma unroll
        for (int f = 0; f < NFRAG; ++f) {
            if (!SPLIT || col[f] < N1) {
                #pragma unroll
                for (int r = 0; r < 4; ++r) {
                    float v = acc[f][r] + bv[f];
                    if (ADD_RES) v += rres[f][r];
                    Asu[(quad * 4 + r) * 264 + col[f]] = f2b(v);
                }
            }
        }
        __syncthreads();
        if constexpr (HMAJOR) {
            // [h][Mtot][32]: per head, 16 rows x 64 B contiguous (1 KB)
            const int h = tid >> 5;
            const int t32 = tid & 31;
            bf16* dsth = C1 + ((size_t)h * Mtot + bm) * 32;
            #pragma unroll
            for (int s = 0; s < 2; ++s) {
                const int o16 = t32 + s * 32;        // 16B chunk id, 0..63
                const int row = o16 >> 2;
                const int ch8 = (o16 & 3) * 8;
                *(s8v*)(dsth + (size_t)row * 32 + ch8) =
                    *(const s8v*)(Asu + row * 264 + h * 32 + ch8);
            }
        } else {
            // plain bf16 [M][256]
            const int row = tid >> 4;            // 0..15
            const int c16 = tid & 15;
            bf16* dst = C1 + (size_t)(bm + row) * 256;
            #pragma unroll
            for (int s = 0; s < 2; ++s) {
                const int eo = (c16 + s * 16) * 8;
                *(s8v*)(dst + eo) = *(const s8v*)(Asu + row * 264 + eo);
            }
        }
        if constexpr (SPLIT) {
            __syncthreads();
            #pragma unroll
            for (int f = 0; f < NFRAG; ++f) {
                if (col[f] >= N1) {
                    #pragma unroll
                    for (int r = 0; r < 4; ++r) {
                        float v = acc[f][r] + bv[f];
                        Asu[(quad * 4 + r) * 264 + (col[f] - N1)] = f2b(v);
                    }
                }
            }
            __syncthreads();
            // HM2 [h][Mtot][16]: per head, 16 rows x 32 B contiguous (512 B)
            const int h = tid >> 5;
            const int t32 = tid & 31;
            bf16* dsth = C2 + ((size_t)h * Mtot + bm) * 16;
            const int row = t32 >> 1;
            const int ch8 = (t32 & 1) * 8;
            *(s8v*)(dsth + (size_t)row * 16 + ch8) =
                *(const s8v*)(Asu + row * 264 + h * 16 + ch8);
        }
    }
}

// Merged GEMM1+GEMM2: blocks [0,nb1) -> vproj; [nb1,2*nb1) -> osb|logits.
__global__ __launch_bounds__(256) void k_gemm12(
    const unsigned* __restrict__ qd,
    const void* value, const void* query, const void* query_pos,
    const bf16* c_wv, const bf16* c_bv, bf16* vproj,
    const bf16* c_wo, const bf16* c_bo, bf16* osb,
    const bf16* c_wa, const bf16* c_ba, bf16* logit,
    int nb1, int Mtot)
{
    __shared__ __align__(16) unsigned short As[16 * 264];   // 8,448 B
    const bool isb = detect_bf16(qd);
    if ((int)blockIdx.x < nb1) {
        const int bm = blockIdx.x * 16;
        if (isb)
            mfma_gemm_body<bf16, float, bf16, 4, false, false, false, true, false, false>(As, bm,
                (const bf16*)value, nullptr, c_wv, c_bv, vproj, 256,
                nullptr, nullptr, nullptr, 0, nullptr, Mtot);
        else
            mfma_gemm_body<float, float, bf16, 4, false, false, false, true, false, false>(As, bm,
                (const float*)value, nullptr, c_wv, c_bv, vproj, 256,
                nullptr, nullptr, nullptr, 0, nullptr, Mtot);
    } else {
        const int bm = (blockIdx.x - nb1) * 16;
        if (isb)
            mfma_gemm_body<bf16, float, bf16, 6, true, true, false, true, true, false>(As, bm,
                (const bf16*)query, (const bf16*)query_pos, c_wo, c_bo, osb, 256,
                c_wa, c_ba, logit, 128, nullptr, Mtot);
        else
            mfma_gemm_body<float, float, bf16, 6, true, true, false, true, true, false>(As, bm,
                (const float*)query, (const float*)query_pos, c_wo, c_bo, osb, 256,
                c_wa, c_ba, logit, 128, nullptr, Mtot);
    }
}

// Final GEMM: A (sampled) is head-major bf16; Res and d_out input-typed.
__global__ __launch_bounds__(256) void k_gemm_final(
    const unsigned* __restrict__ qd, const bf16* A1,
    const bf16* W, const bf16* bias, const void* Res, void* C, int Mtot)
{
    __shared__ __align__(16) unsigned short As[32 * 264];   // 16,896 B (f32 C-stage)
    const int bm = blockIdx.x * 16;
    if (detect_bf16(qd))
        mfma_gemm_body<bf16, bf16, bf16, 4, false, false, true, false, false, true>(As, bm,
            A1, nullptr, W, bias, (bf16*)C, 256,
            nullptr, nullptr, nullptr, 0, (const bf16*)Res, Mtot);
    else
        mfma_gemm_body<bf16, float, float, 4, false, false, true, false, false, true>(As, bm,
            A1, nullptr, W, bias, (float*)C, 256,
            nullptr, nullptr, nullptr, 0, (const float*)Res, Mtot);
}

// ---- sampler ------------------------------------------------------------
// Block 256 = 32 queries x 8 lanes, ONE head per block (head = bid&7 ->
// XCD-pinned; R2 verified: FETCH 113.8 -> 16.4 MB).
// R3 (verified: 53.6 -> <41 us): x-corner pair loads + 32-deep MLP.
struct SampLds {
    float    swgt[16][32][4];   // [tap][pair][wA*cy0, wB*cy0, wA*cy1, wB*cy1]
    unsigned sidx[16][32][2];   // [tap][pair][row y0, row y1] plane-rel bytes
};   // 12,288 B

__global__ __launch_bounds__(256) void k_sample(
    const unsigned* __restrict__ qd, const bf16* __restrict__ vproj,
    bf16* __restrict__ osb, const bf16* __restrict__ logits,
    const void* __restrict__ refp, int Mtot)
{
    __shared__ SampLds L;
    const bool isb = detect_bf16(qd);
    const int t  = threadIdx.x;
    const int p  = t >> 3;               // pair (query within block) 0..31
    const int dg = t & 7;                // lane within pair
    const int head = blockIdx.x & 7;     // XCD-pinned under round-robin
    const int qc   = blockIdx.x >> 3;
    const int q = qc * 32 + p;
    const size_t hm = (size_t)head * (size_t)Mtot;   // head plane key base

    // own 2 taps' offsets: elements 4dg..4dg+3 of the (q,h) 32-elem slice
    float f0, f1, f2, f3;
    {
        ushort4 u = *(const ushort4*)(osb + (hm + q) * 32 + dg * 4);
        f0 = b2f(u.x); f1 = b2f(u.y); f2 = b2f(u.z); f3 = b2f(u.w);
    }

    // softmax over the 16 logits of (q,h): lane dg holds logits 2dg,2dg+1
    float p0, p1;
    {
        ushort2 lu = *(const ushort2*)(logits + (hm + q) * 16 + dg * 2);
        float l0 = b2f(lu.x), l1 = b2f(lu.y);
        float mx = fmaxf(l0, l1);
        mx = fmaxf(mx, __shfl_xor(mx, 1));
        mx = fmaxf(mx, __shfl_xor(mx, 2));
        mx = fmaxf(mx, __shfl_xor(mx, 4));
        float e0 = __expf(l0 - mx), e1 = __expf(l1 - mx);
        float s = e0 + e1;
        s += __shfl_xor(s, 1);
        s += __shfl_xor(s, 2);
        s += __shfl_xor(s, 4);
        const float inv = 1.f / s;
        p0 = e0 * inv; p1 = e1 * inv;
    }

    // reference point: both taps of this lane share level lv = dg>>1
    const int lv = dg >> 1;
    float rx, ry;
    if (isb) {
        rx = ld1((const bf16*)refp + (size_t)q * 8 + 2 * lv);
        ry = ld1((const bf16*)refp + (size_t)q * 8 + 2 * lv + 1);
    } else {
        rx = ld1((const float*)refp + (size_t)q * 8 + 2 * lv);
        ry = ld1((const float*)refp + (size_t)q * 8 + 2 * lv + 1);
    }

    // tap precompute: lane dg owns taps i = 2dg, 2dg+1
    #pragma unroll
    for (int tt = 0; tt < 2; ++tt) {
        const int i = dg * 2 + tt;             // (l,p) in [0,16)
        const int l = i >> 2;                  // == lv
        const int WW = 128 >> l;
        const int st = (l == 0) ? 0 : (l == 1) ? 16384 : (l == 2) ? 20480 : 21504;
        const float ox = tt ? f2 : f0;
        const float oy = tt ? f3 : f1;
        const float aw = tt ? p1 : p0;
        const float gx = rx * (float)WW + ox - 0.5f;
        const float gy = ry * (float)WW + oy - 0.5f;
        const float x0f = floorf(gx);
        const float y0f = floorf(gy);
        const float wx = gx - x0f;
        const float wy = gy - y0f;
        const int x0 = (int)x0f;
        const int y0 = (int)y0f;
        // x-corner folding: base key bx; lanes-lo weight uA, lanes-hi uB.
        const float ux0 = (x0 >= 0 && x0 < WW) ? (1.f - wx) : 0.f;
        const float ux1 = (x0 + 1 >= 0 && x0 + 1 < WW) ? wx : 0.f;
        const float uA = (x0 >= 0) ? ux0 : ux1;
        const float uB = (x0 >= 0) ? ux1 : 0.f;
        const int bx = min(max(x0, 0), WW - 1);
        const float vy0 = (y0 >= 0 && y0 < WW) ? 1.f : 0.f;
        const float vy1 = (y0 + 1 >= 0 && y0 + 1 < WW) ? 1.f : 0.f;
        const int yc0 = min(max(y0, 0), WW - 1);
        const int yc1 = min(max(y0 + 1, 0), WW - 1);
        const float cy0 = (1.f - wy) * vy0 * aw;
        const float cy1 = wy * vy1 * aw;
        *(float4*)L.swgt[i][p] = make_float4(uA * cy0, uB * cy0, uA * cy1, uB * cy1);
        *(uint2*)L.sidx[i][p] = make_uint2(
            (unsigned)(st + yc0 * WW + bx) * 64u,
            (unsigned)(st + yc1 * WW + bx) * 64u);
    }
    __syncthreads();

    // gather: lane dg covers 8 channels of key bx (dg<4) or bx+1 (dg>=4)
    const unsigned hb = (unsigned)(hm * 64) + (unsigned)dg * 16u;
    const char* vb = (const char*)vproj;

    uint2 iv[16];
    #pragma unroll
    for (int i = 0; i < 16; ++i) iv[i] = *(const uint2*)L.sidx[i][p];

    s8v r0[16], r1[16];
    #pragma unroll
    for (int i = 0; i < 16; ++i) {
        r0[i] = *(const s8v*)(vb + (size_t)(iv[i].x + hb));
        r1[i] = *(const s8v*)(vb + (size_t)(iv[i].y + hb));
    }

    const bool lo = (dg < 4);
    float acc[8] = {0.f, 0.f, 0.f, 0.f, 0.f, 0.f, 0.f, 0.f};
    #pragma unroll
    for (int i = 0; i < 16; ++i) {
        const float4 w = *(const float4*)L.swgt[i][p];
        const float w0 = lo ? w.x : w.y;
        const float w1 = lo ? w.z : w.w;
        #pragma unroll
        for (int k = 0; k < 8; ++k)
            acc[k] = fmaf(w0, b2f((unsigned short)r0[i][k]), acc[k]);
        #pragma unroll
        for (int k = 0; k < 8; ++k)
            acc[k] = fmaf(w1, b2f((unsigned short)r1[i][k]), acc[k]);
    }

    // merge x-lo/x-hi half-sums: partner lane dg^4 has same channels
    #pragma unroll
    for (int k = 0; k < 8; ++k) acc[k] += __shfl_xor(acc[k], 4);

    if (dg < 4) {   // lanes 0-3 write the 64-B sampled row (8 ch each)
        s8v o;
        #pragma unroll
        for (int k = 0; k < 8; ++k) o[k] = (short)f2b(acc[k]);
        *(s8v*)(osb + (hm + q) * 32 + dg * 8) = o;
    }
}

extern "C" void kernel_launch(void* const* d_in, const int* in_sizes, int n_in,
                              void* d_out, int out_size, void* d_ws, size_t ws_size,
                              hipStream_t stream) {
    const void* query     = d_in[0];
    const void* query_pos = d_in[1];
    const void* value     = d_in[2];
    const void* refp      = d_in[3];
    const void* W_value = d_in[5];
    const void* b_value = d_in[6];
    const void* W_off   = d_in[7];
    const void* b_off   = d_in[8];
    const void* W_attn  = d_in[9];
    const void* b_attn  = d_in[10];
    const void* W_out   = d_in[11];
    const void* b_out   = d_in[12];
    const unsigned* qd = (const unsigned*)d_in[0];

    const int M = in_sizes[0] / 256;   // 21760 = 16*1360 = 4*5440
    char* wsb = (char*)d_ws;

    // ws: vproj (head-major [8][M][32]) | osb (HM offsets->sampled in-place)
    //     | wc2 (W_out cache, own slot -> prep can run up-front)
    bf16* vproj = (bf16*)wsb;                        // M*512 B
    bf16* osb   = (bf16*)(wsb + (size_t)M * 512);    // M*512 B
    bf16* wc2   = (bf16*)(wsb + (size_t)M * 1024);   // 131,584 B
    // d_out scratch: logits head-major [8][M][16] in [0, M*256 B); wc1 at +8 MB.
    bf16* logit = (bf16*)d_out;
    bf16* wc1   = (bf16*)((char*)d_out + (8u << 20));
    const bf16* c_wv = wc1;
    const bf16* c_wo = wc1 + 65536;
    const bf16* c_wa = wc1 + 131072;
    const bf16* c_bv = wc1 + 163840;
    const bf16* c_bo = wc1 + 164096;
    const bf16* c_ba = wc1 + 164352;

    dim3 blk(256, 1, 1);
    const int nb1 = M / 16;                          // 1360
    dim3 g12((unsigned)(2 * nb1), 1, 1);             // merged GEMM1+GEMM2
    dim3 g16((unsigned)nb1, 1, 1);
    dim3 gs((unsigned)(M / 4), 1, 1);                // = 8*(M/32): head = bid&7

    // 0) all weights -> bf16 caches (single launch)
    k_prep<<<dim3((P_TOTAL / 4 + 255) / 256), blk, 0, stream>>>(qd,
        W_value, W_off, W_attn, b_value, b_off, b_attn, W_out, b_out, wc1, wc2);
    // 1+2) merged: vproj GEMM || offsets/logits GEMM (independent)
    k_gemm12<<<g12, blk, 0, stream>>>(qd, value, query, query_pos,
        c_wv, c_bv, vproj, c_wo, c_bo, osb, c_wa, c_ba, logit, nb1, M);
    // 3) softmax + bilinear sampling (in-place osb, head-per-XCD blocks)
    k_sample<<<gs, blk, 0, stream>>>(qd, vproj, osb, logit, refp, M);
    // 4) out = sampled(HM) @ W_out^T + b_out + query -> d_out
    k_gemm_final<<<g16, blk, 0, stream>>>(qd, osb, wc2, wc2 + 65536, query, d_out, M);
}

// Round 8
// 194.496 us; speedup vs baseline: 1.1699x; 1.1699x over previous
//
#include <hip/hip_runtime.h>
#include <hip/hip_bf16.h>
#include <math.h>
#include <type_traits>

#define K_DIM 256
using bf16 = __hip_bfloat16;

typedef __attribute__((ext_vector_type(8))) short s8v;   // 8 bf16 (4 VGPRs)
typedef __attribute__((ext_vector_type(4))) float f4v;   // 4 f32 acc

// ---- dtype helpers ------------------------------------------------------
__device__ __forceinline__ float b2f(unsigned short u) {
    return __uint_as_float(((unsigned)u) << 16);
}
__device__ __forceinline__ unsigned short f2b(float f) {   // RNE f32->bf16
    unsigned u = __float_as_uint(f);
    unsigned r = 0x7FFFu + ((u >> 16) & 1u);
    return (unsigned short)((u + r) >> 16);
}
__device__ __forceinline__ float  ld1(const float* p) { return *p; }
__device__ __forceinline__ float  ld1(const bf16*  p) { return b2f(*(const unsigned short*)p); }
__device__ __forceinline__ float4 ld4(const float* p) { return *(const float4*)p; }
__device__ __forceinline__ float4 ld4(const bf16*  p) {
    ushort4 u = *(const ushort4*)p;
    return make_float4(b2f(u.x), b2f(u.y), b2f(u.z), b2f(u.w));
}
__device__ __forceinline__ s8v ldw8(const bf16* p) { return *(const s8v*)p; }

// ---- runtime dtype detection --------------------------------------------
__device__ __forceinline__ bool detect_bf16(const unsigned* __restrict__ qw) {
    unsigned w = qw[threadIdx.x & 63];
    unsigned t = (w >> 8) & 0x7F;
    bool hit = (t >= 0x3Bu) && (t <= 0x42u);
    unsigned long long m = __ballot(hit);
    return __popcll(m) >= 32;
}

// ---- weight pre-conversion (single merged kernel) ------------------------
#define P1_TOTAL 164480
#define P_TOTAL  230272
__global__ __launch_bounds__(256) void k_prep(
    const unsigned* __restrict__ qd,
    const void* wv, const void* wo, const void* wa,
    const void* bv, const void* bo, const void* ba,
    const void* wout, const void* bout,
    bf16* __restrict__ dst1, bf16* __restrict__ dst2)
{
    const bool isb = detect_bf16(qd);
    const int i4 = (blockIdx.x * 256 + threadIdx.x) * 4;
    if (i4 >= P_TOTAL) return;
    const void* src; int off; bf16* dst;
    if (i4 < P1_TOTAL) {
        dst = dst1 + i4;
        if      (i4 < 65536)  { src = wv; off = i4; }
        else if (i4 < 131072) { src = wo; off = i4 - 65536; }
        else if (i4 < 163840) { src = wa; off = i4 - 131072; }
        else if (i4 < 164096) { src = bv; off = i4 - 163840; }
        else if (i4 < 164352) { src = bo; off = i4 - 164096; }
        else                  { src = ba; off = i4 - 164352; }
    } else {
        const int j = i4 - P1_TOTAL;
        dst = dst2 + j;
        if (j < 65536) { src = wout; off = j; }
        else           { src = bout; off = j - 65536; }
    }
    if (isb) {
        *(ushort4*)dst = *(const ushort4*)((const unsigned short*)src + off);
    } else {
        float4 v = *(const float4*)((const float*)src + off);
        *(ushort4*)dst = make_ushort4(f2b(v.x), f2b(v.y), f2b(v.z), f2b(v.w));
    }
}

// ---- MFMA GEMM ----------------------------------------------------------
// R8: M=64 TILES. R7 falsified the occupancy theory (occ 22->40%, dur
// WORSE): the invariant cost is per-block weight-panel reads (128-192KB
// from L2, 16 scattered lines per ldw8 -> L1-miss line throughput is the
// shared bottleneck; total weight lines scale with #blocks). M=64 -> each
// weight fragment feeds 4 MFMAs; weight-line traffic halves vs M=32 and
// quarters vs M=16. A-traffic unchanged.
// HMAJOR: C1 written head-major [h=c>>5][Mtot][32ch].
// HM2:    C2 written head-major [h=cc>>4][Mtot][16].
// A1HM:   A1 read head-major [h][Mtot][32] (bf16 fast path only).
// ADD_RES: residual folded in during the row-linear copy phase (coalesced).
template<typename AT, typename RT, typename CT, int NFRAG, bool ADD_A2, bool SPLIT,
         bool ADD_RES, bool HMAJOR, bool HM2, bool A1HM>
__device__ __forceinline__ void mfma_gemm_body(
    unsigned short* __restrict__ As, int bm,
    const AT* __restrict__ A1, const AT* __restrict__ A2,
    const bf16* __restrict__ W1, const bf16* __restrict__ bias1, CT* __restrict__ C1, int N1,
    const bf16* __restrict__ W2, const bf16* __restrict__ bias2, bf16* __restrict__ C2, int N2,
    const RT* __restrict__ Res, int Mtot)
{
    const int tid = threadIdx.x;

    {   // stage A(+A2) -> bf16 LDS; 64 rows x 256 cols
        const AT* t1 = A1 + (size_t)bm * K_DIM;
        if constexpr (!ADD_A2 && std::is_same<AT, bf16>::value) {
            s8v r[8];
            #pragma unroll
            for (int j = 0; j < 8; ++j) {
                const int e = j * 2048 + tid * 8;
                const int row = e >> 8, col = e & 255;
                const bf16* src;
                if constexpr (A1HM)
                    src = (const bf16*)A1 +
                          ((size_t)(col >> 5) * (size_t)Mtot + (size_t)(bm + row)) * 32 + (col & 31);
                else
                    src = t1 + e;
                r[j] = *(const s8v*)src;
            }
            #pragma unroll
            for (int j = 0; j < 8; ++j) {
                const int e = j * 2048 + tid * 8;
                *(s8v*)&As[(e >> 8) * 264 + (e & 255)] = r[j];
            }
        } else {
            const AT* t2 = ADD_A2 ? (A2 + (size_t)bm * K_DIM) : (const AT*)0;
            #pragma unroll
            for (int jb = 0; jb < 4; ++jb) {
                float4 ra[4], rb[4];
                #pragma unroll
                for (int j = 0; j < 4; ++j)
                    ra[j] = ld4(t1 + (jb * 4 + j) * 1024 + tid * 4);
                if (ADD_A2) {
                    #pragma unroll
                    for (int j = 0; j < 4; ++j)
                        rb[j] = ld4(t2 + (jb * 4 + j) * 1024 + tid * 4);
                }
                #pragma unroll
                for (int j = 0; j < 4; ++j) {
                    const int e = (jb * 4 + j) * 1024 + tid * 4;
                    float4 v = ra[j];
                    if (ADD_A2) { v.x += rb[j].x; v.y += rb[j].y; v.z += rb[j].z; v.w += rb[j].w; }
                    *(ushort4*)&As[(e >> 8) * 264 + (e & 255)] =
                        make_ushort4(f2b(v.x), f2b(v.y), f2b(v.z), f2b(v.w));
                }
            }
        }
    }

    const int wv = tid >> 6;
    const int lane = tid & 63;
    const int n15 = lane & 15;
    const int quad = lane >> 4;

    const bf16* Wr[NFRAG];
    int col[NFRAG];
    #pragma unroll
    for (int f = 0; f < NFRAG; ++f) {
        const int c = (wv * NFRAG + f) * 16 + n15;
        col[f] = c;
        if (SPLIT && c >= N1) Wr[f] = W2 + (size_t)(c - N1) * K_DIM;
        else                  Wr[f] = W1 + (size_t)c * K_DIM;
    }

    // prefetch: first weight fragments + bias (latency hides under barrier)
    s8v bcur[NFRAG], bnxt[NFRAG];
    #pragma unroll
    for (int f = 0; f < NFRAG; ++f) bcur[f] = ldw8(Wr[f] + quad * 8);

    float bv[NFRAG];
    #pragma unroll
    for (int f = 0; f < NFRAG; ++f) {
        const int c = col[f];
        const bool hi = SPLIT && (c >= N1);
        bv[f] = hi ? ld1(bias2 + (c - N1)) : ld1(bias1 + c);
    }

    __syncthreads();

    const f4v zz = {0.f, 0.f, 0.f, 0.f};
    f4v acc[4][NFRAG];
    #pragma unroll
    for (int mi = 0; mi < 4; ++mi)
        #pragma unroll
        for (int f = 0; f < NFRAG; ++f) acc[mi][f] = zz;

    #pragma unroll
    for (int kk = 0; kk < 8; ++kk) {
        const int k0 = kk * 32 + quad * 8;
        if (kk < 7) {
            #pragma unroll
            for (int f = 0; f < NFRAG; ++f) bnxt[f] = ldw8(Wr[f] + k0 + 32);
        }
        s8v a[4];
        #pragma unroll
        for (int mi = 0; mi < 4; ++mi)
            a[mi] = *(const s8v*)&As[(mi * 16 + n15) * 264 + k0];
        #pragma unroll
        for (int mi = 0; mi < 4; ++mi)
            #pragma unroll
            for (int f = 0; f < NFRAG; ++f)
                acc[mi][f] = __builtin_amdgcn_mfma_f32_16x16x32_bf16(a[mi], bcur[f], acc[mi][f], 0, 0, 0);
        if (kk < 7) {
            #pragma unroll
            for (int f = 0; f < NFRAG; ++f) bcur[f] = bnxt[f];
        }
    }

    // ---- coalesced epilogue via LDS C-staging (As is dead) ----
    __syncthreads();   // all waves done reading As

    if constexpr (ADD_RES) {
        // final GEMM: 4 passes of 16 rows; f32 staging; Res folded in the
        // row-linear copy (coalesced loads, single rounding point).
        float* Asf = (float*)As;
        #pragma unroll
        for (int mi = 0; mi < 4; ++mi) {
            #pragma unroll
            for (int f = 0; f < NFRAG; ++f)
                #pragma unroll
                for (int r = 0; r < 4; ++r)
                    Asf[(quad * 4 + r) * 264 + col[f]] = acc[mi][f][r] + bv[f];
            __syncthreads();
            #pragma unroll
            for (int s = 0; s < 4; ++s) {
                const int idx = s * 256 + tid;   // 0..1023
                const int row = idx >> 6;        // 0..15
                const int c16 = idx & 63;        // 16B chunk in row (f32)
                float4 o = *(const float4*)(Asf + row * 264 + c16 * 4);
                const size_t m = (size_t)(bm + mi * 16 + row);
                if constexpr (std::is_same<RT, bf16>::value) {
                    ushort4 ru = *(const ushort4*)((const bf16*)Res + m * 256 + c16 * 4);
                    o.x += b2f(ru.x); o.y += b2f(ru.y); o.z += b2f(ru.z); o.w += b2f(ru.w);
                } else {
                    float4 rf = *(const float4*)((const float*)Res + m * 256 + c16 * 4);
                    o.x += rf.x; o.y += rf.y; o.z += rf.z; o.w += rf.w;
                }
                if constexpr (std::is_same<CT, float>::value)
                    *(float4*)((float*)C1 + m * 256 + c16 * 4) = o;
                else
                    *(ushort4*)((bf16*)C1 + m * 256 + c16 * 4) =
                        make_ushort4(f2b(o.x), f2b(o.y), f2b(o.z), f2b(o.w));
            }
            __syncthreads();
        }
    } else {
        unsigned short* Asu = As;
        // stage C1 cols (c < N1): 64 rows
        #pragma unroll
        for (int f = 0; f < NFRAG; ++f) {
            if (!SPLIT || col[f] < N1) {
                #pragma unroll
                for (int mi = 0; mi < 4; ++mi)
                    #pragma unroll
                    for (int r = 0; r < 4; ++r)
                        Asu[(mi * 16 + quad * 4 + r) * 264 + col[f]] =
                            f2b(acc[mi][f][r] + bv[f]);
            }
        }
        __syncthreads();
        if constexpr (HMAJOR) {
            // [h][Mtot][32]: per head, 64 rows x 64 B = 4 KB contiguous
            const int h = tid >> 5;
            const int t32 = tid & 31;
            bf16* dsth = C1 + ((size_t)h * Mtot + bm) * 32;
            #pragma unroll
            for (int s = 0; s < 8; ++s) {
                const int o16 = t32 + s * 32;        // 0..255
                const int row = o16 >> 2;
                const int ch8 = (o16 & 3) * 8;
                *(s8v*)(dsth + (size_t)row * 32 + ch8) =
                    *(const s8v*)(Asu + row * 264 + h * 32 + ch8);
            }
        } else {
            // plain bf16 [M][256]
            #pragma unroll
            for (int s = 0; s < 8; ++s) {
                const int idx = s * 256 + tid;       // 0..2047
                const int row = idx >> 5;            // 0..63
                const int c16 = idx & 31;
                *(s8v*)(C1 + (size_t)(bm + row) * 256 + c16 * 8) =
                    *(const s8v*)(Asu + row * 264 + c16 * 8);
            }
        }
        if constexpr (SPLIT) {
            __syncthreads();
            #pragma unroll
            for (int f = 0; f < NFRAG; ++f) {
                if (col[f] >= N1) {
                    #pragma unroll
                    for (int mi = 0; mi < 4; ++mi)
                        #pragma unroll
                        for (int r = 0; r < 4; ++r)
                            Asu[(mi * 16 + quad * 4 + r) * 264 + (col[f] - N1)] =
                                f2b(acc[mi][f][r] + bv[f]);
                }
            }
            __syncthreads();
            // HM2 [h][Mtot][16]: per head, 64 rows x 32 B = 2 KB contiguous
            const int h = tid >> 5;
            const int t32 = tid & 31;
            bf16* dsth = C2 + ((size_t)h * Mtot + bm) * 16;
            #pragma unroll
            for (int s = 0; s < 4; ++s) {
                const int o16 = t32 + s * 32;        // 0..127
                const int row = o16 >> 1;
                const int ch8 = (o16 & 1) * 8;
                *(s8v*)(dsth + (size_t)row * 16 + ch8) =
                    *(const s8v*)(Asu + row * 264 + h * 16 + ch8);
            }
        }
    }
}

// Merged GEMM1+GEMM2: blocks [0,nb1) -> vproj; [nb1,2*nb1) -> osb|logits.
__global__ __launch_bounds__(256) void k_gemm12(
    const unsigned* __restrict__ qd,
    const void* value, const void* query, const void* query_pos,
    const bf16* c_wv, const bf16* c_bv, bf16* vproj,
    const bf16* c_wo, const bf16* c_bo, bf16* osb,
    const bf16* c_wa, const bf16* c_ba, bf16* logit,
    int nb1, int Mtot)
{
    __shared__ __align__(16) unsigned short As[64 * 264];   // 33,792 B
    const bool isb = detect_bf16(qd);
    if ((int)blockIdx.x < nb1) {
        const int bm = blockIdx.x * 64;
        if (isb)
            mfma_gemm_body<bf16, float, bf16, 4, false, false, false, true, false, false>(As, bm,
                (const bf16*)value, nullptr, c_wv, c_bv, vproj, 256,
                nullptr, nullptr, nullptr, 0, nullptr, Mtot);
        else
            mfma_gemm_body<float, float, bf16, 4, false, false, false, true, false, false>(As, bm,
                (const float*)value, nullptr, c_wv, c_bv, vproj, 256,
                nullptr, nullptr, nullptr, 0, nullptr, Mtot);
    } else {
        const int bm = (blockIdx.x - nb1) * 64;
        if (isb)
            mfma_gemm_body<bf16, float, bf16, 6, true, true, false, true, true, false>(As, bm,
                (const bf16*)query, (const bf16*)query_pos, c_wo, c_bo, osb, 256,
                c_wa, c_ba, logit, 128, nullptr, Mtot);
        else
            mfma_gemm_body<float, float, bf16, 6, true, true, false, true, true, false>(As, bm,
                (const float*)query, (const float*)query_pos, c_wo, c_bo, osb, 256,
                c_wa, c_ba, logit, 128, nullptr, Mtot);
    }
}

// Final GEMM: A (sampled) is head-major bf16; Res and d_out input-typed.
__global__ __launch_bounds__(256) void k_gemm_final(
    const unsigned* __restrict__ qd, const bf16* A1,
    const bf16* W, const bf16* bias, const void* Res, void* C, int Mtot)
{
    __shared__ __align__(16) unsigned short As[64 * 264];   // 33,792 B
    const int bm = blockIdx.x * 64;
    if (detect_bf16(qd))
        mfma_gemm_body<bf16, bf16, bf16, 4, false, false, true, false, false, true>(As, bm,
            A1, nullptr, W, bias, (bf16*)C, 256,
            nullptr, nullptr, nullptr, 0, (const bf16*)Res, Mtot);
    else
        mfma_gemm_body<bf16, float, float, 4, false, false, true, false, false, true>(As, bm,
            A1, nullptr, W, bias, (float*)C, 256,
            nullptr, nullptr, nullptr, 0, (const float*)Res, Mtot);
}

// ---- sampler ------------------------------------------------------------
// Block 256 = 32 queries x 8 lanes, ONE head per block (head = bid&7 ->
// XCD-pinned; R2 verified: FETCH 113.8 -> 16.4 MB).
// R3 (verified: 53.6 -> <41 us): x-corner pair loads + 32-deep MLP.
struct SampLds {
    float    swgt[16][32][4];   // [tap][pair][wA*cy0, wB*cy0, wA*cy1, wB*cy1]
    unsigned sidx[16][32][2];   // [tap][pair][row y0, row y1] plane-rel bytes
};   // 12,288 B

__global__ __launch_bounds__(256) void k_sample(
    const unsigned* __restrict__ qd, const bf16* __restrict__ vproj,
    bf16* __restrict__ osb, const bf16* __restrict__ logits,
    const void* __restrict__ refp, int Mtot)
{
    __shared__ SampLds L;
    const bool isb = detect_bf16(qd);
    const int t  = threadIdx.x;
    const int p  = t >> 3;               // pair (query within block) 0..31
    const int dg = t & 7;                // lane within pair
    const int head = blockIdx.x & 7;     // XCD-pinned under round-robin
    const int qc   = blockIdx.x >> 3;
    const int q = qc * 32 + p;
    const size_t hm = (size_t)head * (size_t)Mtot;   // head plane key base

    // own 2 taps' offsets: elements 4dg..4dg+3 of the (q,h) 32-elem slice
    float f0, f1, f2, f3;
    {
        ushort4 u = *(const ushort4*)(osb + (hm + q) * 32 + dg * 4);
        f0 = b2f(u.x); f1 = b2f(u.y); f2 = b2f(u.z); f3 = b2f(u.w);
    }

    // softmax over the 16 logits of (q,h): lane dg holds logits 2dg,2dg+1
    float p0, p1;
    {
        ushort2 lu = *(const ushort2*)(logits + (hm + q) * 16 + dg * 2);
        float l0 = b2f(lu.x), l1 = b2f(lu.y);
        float mx = fmaxf(l0, l1);
        mx = fmaxf(mx, __shfl_xor(mx, 1));
        mx = fmaxf(mx, __shfl_xor(mx, 2));
        mx = fmaxf(mx, __shfl_xor(mx, 4));
        float e0 = __expf(l0 - mx), e1 = __expf(l1 - mx);
        float s = e0 + e1;
        s += __shfl_xor(s, 1);
        s += __shfl_xor(s, 2);
        s += __shfl_xor(s, 4);
        const float inv = 1.f / s;
        p0 = e0 * inv; p1 = e1 * inv;
    }

    // reference point: both taps of this lane share level lv = dg>>1
    const int lv = dg >> 1;
    float rx, ry;
    if (isb) {
        rx = ld1((const bf16*)refp + (size_t)q * 8 + 2 * lv);
        ry = ld1((const bf16*)refp + (size_t)q * 8 + 2 * lv + 1);
    } else {
        rx = ld1((const float*)refp + (size_t)q * 8 + 2 * lv);
        ry = ld1((const float*)refp + (size_t)q * 8 + 2 * lv + 1);
    }

    // tap precompute: lane dg owns taps i = 2dg, 2dg+1
    #pragma unroll
    for (int tt = 0; tt < 2; ++tt) {
        const int i = dg * 2 + tt;             // (l,p) in [0,16)
        const int l = i >> 2;                  // == lv
        const int WW = 128 >> l;
        const int st = (l == 0) ? 0 : (l == 1) ? 16384 : (l == 2) ? 20480 : 21504;
        const float ox = tt ? f2 : f0;
        const float oy = tt ? f3 : f1;
        const float aw = tt ? p1 : p0;
        const float gx = rx * (float)WW + ox - 0.5f;
        const float gy = ry * (float)WW + oy - 0.5f;
        const float x0f = floorf(gx);
        const float y0f = floorf(gy);
        const float wx = gx - x0f;
        const float wy = gy - y0f;
        const int x0 = (int)x0f;
        const int y0 = (int)y0f;
        // x-corner folding: base key bx; lanes-lo weight uA, lanes-hi uB.
        const float ux0 = (x0 >= 0 && x0 < WW) ? (1.f - wx) : 0.f;
        const float ux1 = (x0 + 1 >= 0 && x0 + 1 < WW) ? wx : 0.f;
        const float uA = (x0 >= 0) ? ux0 : ux1;
        const float uB = (x0 >= 0) ? ux1 : 0.f;
        const int bx = min(max(x0, 0), WW - 1);
        const float vy0 = (y0 >= 0 && y0 < WW) ? 1.f : 0.f;
        const float vy1 = (y0 + 1 >= 0 && y0 + 1 < WW) ? 1.f : 0.f;
        const int yc0 = min(max(y0, 0), WW - 1);
        const int yc1 = min(max(y0 + 1, 0), WW - 1);
        const float cy0 = (1.f - wy) * vy0 * aw;
        const float cy1 = wy * vy1 * aw;
        *(float4*)L.swgt[i][p] = make_float4(uA * cy0, uB * cy0, uA * cy1, uB * cy1);
        *(uint2*)L.sidx[i][p] = make_uint2(
            (unsigned)(st + yc0 * WW + bx) * 64u,
            (unsigned)(st + yc1 * WW + bx) * 64u);
    }
    __syncthreads();

    // gather: lane dg covers 8 channels of key bx (dg<4) or bx+1 (dg>=4)
    const unsigned hb = (unsigned)(hm * 64) + (unsigned)dg * 16u;
    const char* vb = (const char*)vproj;

    uint2 iv[16];
    #pragma unroll
    for (int i = 0; i < 16; ++i) iv[i] = *(const uint2*)L.sidx[i][p];

    s8v r0[16], r1[16];
    #pragma unroll
    for (int i = 0; i < 16; ++i) {
        r0[i] = *(const s8v*)(vb + (size_t)(iv[i].x + hb));
        r1[i] = *(const s8v*)(vb + (size_t)(iv[i].y + hb));
    }

    const bool lo = (dg < 4);
    float acc[8] = {0.f, 0.f, 0.f, 0.f, 0.f, 0.f, 0.f, 0.f};
    #pragma unroll
    for (int i = 0; i < 16; ++i) {
        const float4 w = *(const float4*)L.swgt[i][p];
        const float w0 = lo ? w.x : w.y;
        const float w1 = lo ? w.z : w.w;
        #pragma unroll
        for (int k = 0; k < 8; ++k)
            acc[k] = fmaf(w0, b2f((unsigned short)r0[i][k]), acc[k]);
        #pragma unroll
        for (int k = 0; k < 8; ++k)
            acc[k] = fmaf(w1, b2f((unsigned short)r1[i][k]), acc[k]);
    }

    // merge x-lo/x-hi half-sums: partner lane dg^4 has same channels
    #pragma unroll
    for (int k = 0; k < 8; ++k) acc[k] += __shfl_xor(acc[k], 4);

    if (dg < 4) {   // lanes 0-3 write the 64-B sampled row (8 ch each)
        s8v o;
        #pragma unroll
        for (int k = 0; k < 8; ++k) o[k] = (short)f2b(acc[k]);
        *(s8v*)(osb + (hm + q) * 32 + dg * 8) = o;
    }
}

extern "C" void kernel_launch(void* const* d_in, const int* in_sizes, int n_in,
                              void* d_out, int out_size, void* d_ws, size_t ws_size,
                              hipStream_t stream) {
    const void* query     = d_in[0];
    const void* query_pos = d_in[1];
    const void* value     = d_in[2];
    const void* refp      = d_in[3];
    const void* W_value = d_in[5];
    const void* b_value = d_in[6];
    const void* W_off   = d_in[7];
    const void* b_off   = d_in[8];
    const void* W_attn  = d_in[9];
    const void* b_attn  = d_in[10];
    const void* W_out   = d_in[11];
    const void* b_out   = d_in[12];
    const unsigned* qd = (const unsigned*)d_in[0];

    const int M = in_sizes[0] / 256;   // 21760 = 64*340 = 4*5440
    char* wsb = (char*)d_ws;

    // ws: vproj (head-major [8][M][32]) | osb (HM offsets->sampled in-place)
    //     | wc2 (W_out cache)
    bf16* vproj = (bf16*)wsb;                        // M*512 B
    bf16* osb   = (bf16*)(wsb + (size_t)M * 512);    // M*512 B
    bf16* wc2   = (bf16*)(wsb + (size_t)M * 1024);   // 131,584 B
    // d_out scratch: logits head-major [8][M][16] in [0, M*256 B); wc1 at +8 MB.
    bf16* logit = (bf16*)d_out;
    bf16* wc1   = (bf16*)((char*)d_out + (8u << 20));
    const bf16* c_wv = wc1;
    const bf16* c_wo = wc1 + 65536;
    const bf16* c_wa = wc1 + 131072;
    const bf16* c_bv = wc1 + 163840;
    const bf16* c_bo = wc1 + 164096;
    const bf16* c_ba = wc1 + 164352;

    dim3 blk(256, 1, 1);
    const int nb1 = M / 64;                          // 340
    dim3 g12((unsigned)(2 * nb1), 1, 1);             // merged GEMM1+GEMM2
    dim3 g64((unsigned)nb1, 1, 1);
    dim3 gs((unsigned)(M / 4), 1, 1);                // head = bid&7

    // 0) all weights -> bf16 caches (single launch)
    k_prep<<<dim3((P_TOTAL / 4 + 255) / 256), blk, 0, stream>>>(qd,
        W_value, W_off, W_attn, b_value, b_off, b_attn, W_out, b_out, wc1, wc2);
    // 1+2) merged: vproj GEMM || offsets/logits GEMM (independent)
    k_gemm12<<<g12, blk, 0, stream>>>(qd, value, query, query_pos,
        c_wv, c_bv, vproj, c_wo, c_bo, osb, c_wa, c_ba, logit, nb1, M);
    // 3) softmax + bilinear sampling (in-place osb, head-per-XCD blocks)
    k_sample<<<gs, blk, 0, stream>>>(qd, vproj, osb, logit, refp, M);
    // 4) out = sampled(HM) @ W_out^T + b_out + query -> d_out
    k_gemm_final<<<g64, blk, 0, stream>>>(qd, osb, wc2, wc2 + 65536, query, d_out, M);
}